// Round 13
// baseline (147.520 us; speedup 1.0000x reference)
//
#include <hip/hip_runtime.h>
#include <hip/hip_bf16.h>

// Problem constants
#define DIMD   768
#define HEADS  16
#define HD     48
#define SEQ    2048
#define BATCH  4
#define NTOK   (BATCH * SEQ)     // 8192
#define QKVD   (3 * DIMD)        // 2304

typedef __attribute__((ext_vector_type(8)))  short s16x8;
typedef __attribute__((ext_vector_type(4)))  float f32x4;
typedef __attribute__((ext_vector_type(16))) float f32x16;
typedef unsigned short ushort_t;

static __device__ __forceinline__ unsigned short f2b(float f) {
  union { __hip_bfloat16 b; unsigned short s; } u;
  u.b = __float2bfloat16(f);
  return u.s;
}
static __device__ __forceinline__ float b2f(unsigned short v) {
  union { float f; unsigned u; } x;
  x.u = ((unsigned)v) << 16;
  return x.f;
}
static __device__ __forceinline__ unsigned pk2(float a, float b) {
  return (unsigned)f2b(a) | ((unsigned)f2b(b) << 16);
}

static __device__ __forceinline__ void gload_lds16(const void* g, void* l) {
  __builtin_amdgcn_global_load_lds(
      (const __attribute__((address_space(1))) unsigned int*)g,
      (__attribute__((address_space(3))) unsigned int*)l, 16, 0, 0);
}

// ---------------------------------------------------------------------------
// merged convert kernel (unchanged from round 12)
// ---------------------------------------------------------------------------
#define CVT_NB   (NTOK * DIMD / 8 / 256)          // 3072
#define TQ_NBX   (QKVD / 32)                      // 72
#define TQ_NB    (TQ_NBX * (DIMD / 32))           // 1728
#define TP_NBX   (DIMD / 32)                      // 24
#define TP_NB    (TP_NBX * (DIMD / 32))           // 576

__global__ __launch_bounds__(256) void cvt_all(
    const float* __restrict__ x, ushort_t* __restrict__ xb,
    const float* __restrict__ wq, ushort_t* __restrict__ wqT,
    const float* __restrict__ wp, ushort_t* __restrict__ wpT) {
  __shared__ float T[32][33];
  const int bid = blockIdx.x;
  const int tid = threadIdx.x;

  if (bid < CVT_NB) {
    const int i = bid * 256 + tid;
    float4 a = ((const float4*)x)[i * 2];
    float4 b = ((const float4*)x)[i * 2 + 1];
    s16x8 v;
    v[0] = (short)f2b(a.x); v[1] = (short)f2b(a.y);
    v[2] = (short)f2b(a.z); v[3] = (short)f2b(a.w);
    v[4] = (short)f2b(b.x); v[5] = (short)f2b(b.y);
    v[6] = (short)f2b(b.z); v[7] = (short)f2b(b.w);
    ((s16x8*)xb)[i] = v;
    return;
  }

  const float* in;
  ushort_t* out;
  int R, C, c0, r0;
  if (bid < CVT_NB + TQ_NB) {
    const int b1 = bid - CVT_NB;
    in = wq; out = wqT; R = DIMD; C = QKVD;
    c0 = (b1 % TQ_NBX) * 32; r0 = (b1 / TQ_NBX) * 32;
  } else {
    const int b2 = bid - CVT_NB - TQ_NB;
    in = wp; out = wpT; R = DIMD; C = DIMD;
    c0 = (b2 % TP_NBX) * 32; r0 = (b2 / TP_NBX) * 32;
  }
  const int lc = tid & 31, lr = tid >> 5;
#pragma unroll
  for (int i = 0; i < 4; ++i)
    T[lr + 8 * i][lc] = in[(size_t)(r0 + lr + 8 * i) * C + c0 + lc];
  __syncthreads();
#pragma unroll
  for (int i = 0; i < 4; ++i)
    out[(size_t)(c0 + lr + 8 * i) * R + r0 + lc] = f2b(T[lc][lr + 8 * i]);
}

// ---------------------------------------------------------------------------
// bf16 MFMA GEMM + XCD-bijective swizzle (unchanged from round 12)
// ---------------------------------------------------------------------------
template <int OUT_BF16>
__global__ __launch_bounds__(256) void gemm_bf16(
    const ushort_t* __restrict__ A, const ushort_t* __restrict__ Bt,
    const float* __restrict__ bias, void* __restrict__ Cout,
    int M, int N, int K) {
  __shared__ __align__(16) ushort_t As[128 * 64];
  __shared__ __align__(16) ushort_t Bs[128 * 64];

  const int tid = threadIdx.x;
  const int lane = tid & 63;
  const int w = tid >> 6;

  const int nwg = gridDim.x * gridDim.y;
  int bx = blockIdx.x, by = blockIdx.y;
  if ((nwg & 7) == 0) {
    const int orig = by * gridDim.x + bx;
    const int cpx = nwg >> 3;
    const int nid = (orig & 7) * cpx + (orig >> 3);
    bx = nid % gridDim.x;
    by = nid / gridDim.x;
  }
  const int m0 = by * 128, n0 = bx * 128;
  const int wm = (w >> 1) * 64, wn = (w & 1) * 64;

  const int c16s = (tid & 7) ^ ((tid >> 3) & 7);
  const ushort_t* aSrc = A + (size_t)(m0 + (tid >> 3)) * K + c16s * 8;
  const ushort_t* bSrc = Bt + (size_t)(n0 + (tid >> 3)) * K + c16s * 8;

  f32x4 acc[4][4];
#pragma unroll
  for (int i = 0; i < 4; ++i)
#pragma unroll
    for (int j = 0; j < 4; ++j) {
      acc[i][j][0] = 0.f; acc[i][j][1] = 0.f;
      acc[i][j][2] = 0.f; acc[i][j][3] = 0.f;
    }

  for (int k0 = 0; k0 < K; k0 += 64) {
    __syncthreads();
#pragma unroll
    for (int r = 0; r < 4; ++r) {
      gload_lds16(aSrc + (size_t)(r * 32) * K + k0,
                  (char*)As + (r * 256 + w * 64) * 16);
      gload_lds16(bSrc + (size_t)(r * 32) * K + k0,
                  (char*)Bs + (r * 256 + w * 64) * 16);
    }
    __syncthreads();

#pragma unroll
    for (int ks = 0; ks < 2; ++ks) {
      s16x8 af[4], bfr[4];
#pragma unroll
      for (int i = 0; i < 4; ++i) {
        const int ar = wm + i * 16 + (lane & 15);
        const int ac = (ks * 4 + (lane >> 4)) ^ (ar & 7);
        af[i] = *(const s16x8*)&As[ar * 64 + ac * 8];
        const int br = wn + i * 16 + (lane & 15);
        const int bc = (ks * 4 + (lane >> 4)) ^ (br & 7);
        bfr[i] = *(const s16x8*)&Bs[br * 64 + bc * 8];
      }
#pragma unroll
      for (int i = 0; i < 4; ++i)
#pragma unroll
        for (int j = 0; j < 4; ++j)
          acc[i][j] = __builtin_amdgcn_mfma_f32_16x16x32_bf16(
              af[i], bfr[j], acc[i][j], 0, 0, 0);
    }
  }

  if (OUT_BF16) {
    ushort_t* C = (ushort_t*)Cout;
#pragma unroll
    for (int i = 0; i < 4; ++i)
#pragma unroll
      for (int j = 0; j < 4; ++j) {
        const int col = n0 + wn + j * 16 + (lane & 15);
#pragma unroll
        for (int r = 0; r < 4; ++r) {
          const int row = m0 + wm + i * 16 + (lane >> 4) * 4 + r;
          C[(size_t)row * N + col] = f2b(acc[i][j][r]);
        }
      }
  } else {
    float* C = (float*)Cout;
#pragma unroll
    for (int i = 0; i < 4; ++i)
#pragma unroll
      for (int j = 0; j < 4; ++j) {
        const int col = n0 + wn + j * 16 + (lane & 15);
        const float bv = bias ? bias[col] : 0.f;
#pragma unroll
        for (int r = 0; r < 4; ++r) {
          const int row = m0 + wm + i * 16 + (lane >> 4) * 4 + r;
          C[(size_t)row * N + col] = acc[i][j][r] + bv;
        }
      }
  }
}

// ---------------------------------------------------------------------------
// bf16-MFMA flash attention, round 13 — register diet on the r11 structure:
//  * K staging via global_load_lds into a LINEAR granule layout, double-
//    buffered (2x6KB). Loads for tile t+1 are issued right AFTER the ready
//    barrier, so the vmcnt(0) drain at the next top-barrier lands after a
//    full compute window (no exposed latency). Frees ka regs + K ds_writes,
//    and the QK reader loses its XOR (ds_read at lane-linear addr).
//      granule G = slot*64 + lane: slot in 0..5 handled by wave=slot;
//      key = (slot/3)*32 + (lane&31), d = (slot%3)*16 + (lane>>5)*8
//  * exp2/pack fused into PV per 8-key half: s dies progressively, pw is 4
//    transient words. PV order ks=0,1,2,3 with identical operands -> output
//    bit-identical to r11/r12.
//  Peak live regs ~105 -> target <=128 bucket = 4 waves/SIMD (occ 33->50%).
// ---------------------------------------------------------------------------
#define KVB 64
#define QPW 32
#define QPB 256
#define NT  (SEQ / KVB)

__global__ __launch_bounds__(512) void attn_mfma(const ushort_t* __restrict__ QKV,
                                                 ushort_t* __restrict__ Aout) {
  const int bh = blockIdx.x;   // fast dim: q-tiles of one (b,h) share an XCD
  const int qt = blockIdx.y;
  const int b = bh >> 4, h = bh & 15;
  const int tid  = threadIdx.x;
  const int w    = tid >> 6;      // 0..7
  const int lane = tid & 63;
  const int l31  = lane & 31;
  const int hi   = lane >> 5;

  __shared__ __align__(16) ushort_t Kfrag[2][6 * 64 * 8];  // 2 x 6 KB linear granules
  __shared__ __align__(16) ushort_t Vt2[8 * 65 * 8];       // 8.125 KB [kb][hd(65)][key%8]

  // init Vt2: zero all, BARRIER, ones row hd=48 (r11-verified sequence)
  *(uint4*)&Vt2[tid * 8] = make_uint4(0u, 0u, 0u, 0u);
  if (tid < 8) *(uint4*)&Vt2[4096 + tid * 8] = make_uint4(0u, 0u, 0u, 0u);
  __syncthreads();
  if (tid < 64) Vt2[((tid >> 3) * 65 + 48) * 8 + (tid & 7)] = (ushort_t)0x3F80;

  const ushort_t* qkv_b = QKV + (size_t)b * SEQ * QKVD;

  // --- Q fragments, pre-scaled by SCALE*log2(e) ---
  const float qs = 0.14433756729740643f * 1.44269504088896340f;
  const int qrow = qt * QPB + w * QPW + l31;
  const ushort_t* qsrc = qkv_b + (size_t)qrow * QKVD + h * HD;
  s16x8 qf[3];
#pragma unroll
  for (int ks = 0; ks < 3; ++ks) {
    s16x8 raw = *(const s16x8*)(qsrc + ks * 16 + hi * 8);
    s16x8 v;
#pragma unroll
    for (int j = 0; j < 8; ++j) v[j] = (short)f2b(b2f((unsigned short)raw[j]) * qs);
    qf[ks] = v;
  }

  f32x16 o[2];
#pragma unroll
  for (int mt = 0; mt < 2; ++mt)
#pragma unroll
    for (int r = 0; r < 16; ++r) o[mt][r] = 0.f;

  // --- staging sources (waves 0..5 only) ---
  // K: wave w = slot; lane's global 16B = K[key][d..d+7]
  const int kkey = (w / 3) * 32 + l31;
  const int kd0  = (w % 3) * 16 + hi * 8;
  const ushort_t* kSrc = qkv_b + (size_t)kkey * QKVD + DIMD + h * HD + kd0;
  // V: lane = key row, wave = hd-granule g0=w
  const ushort_t* vSrc = qkv_b + (size_t)lane * QKVD + 2 * DIMD + h * HD + w * 8;

  s16x8 va;
  auto issueK = [&](int kt, int buf) {
    if (w < 6)
      gload_lds16(kSrc + (size_t)(kt * KVB) * QKVD,
                  (char*)&Kfrag[buf][0] + w * 1024);
  };
  auto loadV = [&](int kt) {
    if (w < 6) va = *(const s16x8*)(vSrc + (size_t)(kt * KVB) * QKVD);
  };
  auto writeV = [&]() {
    if (w < 6) {
      const int kb = lane >> 3, k7 = lane & 7;
#pragma unroll
      for (int j = 0; j < 8; ++j)
        Vt2[(kb * 65 + 8 * w + j) * 8 + k7] = (ushort_t)va[j];
    }
  };

  // prologue: tile 0 K-load in flight, V0 in regs
  issueK(0, 0);
  loadV(0);

  for (int kt = 0; kt < NT; ++kt) {
    const int cur = kt & 1;
    __syncthreads();   // A: prev PV readers done; drains K[kt] gload (+V load)
    writeV();          // Vt2 <- va (tile kt)
    __syncthreads();   // B: V ready (K[kt] ready since A)
    if (kt + 1 < NT) {               // VMEM for t+1 fires into the compute window
      issueK(kt + 1, cur ^ 1);
      loadV(kt + 1);
    }
    const ushort_t* kf = &Kfrag[cur][0];

    // ---- QK^T s0 (key block 0: slots 0..2), then fused exp/pack/PV ks=0,1 ----
    f32x16 s0;
#pragma unroll
    for (int r = 0; r < 16; ++r) s0[r] = 0.f;
    __builtin_amdgcn_s_setprio(1);
#pragma unroll
    for (int ks = 0; ks < 3; ++ks) {
      s16x8 a0 = *(const s16x8*)&kf[(ks * 64 + lane) * 8];
      s0 = __builtin_amdgcn_mfma_f32_32x32x16_bf16(a0, qf[ks], s0, 0, 0, 0);
    }
    __builtin_amdgcn_s_setprio(0);
#pragma unroll
    for (int half = 0; half < 2; ++half) {
      unsigned p0 = pk2(__builtin_amdgcn_exp2f(s0[half * 8 + 0]),
                        __builtin_amdgcn_exp2f(s0[half * 8 + 1]));
      unsigned p1 = pk2(__builtin_amdgcn_exp2f(s0[half * 8 + 2]),
                        __builtin_amdgcn_exp2f(s0[half * 8 + 3]));
      unsigned p2 = pk2(__builtin_amdgcn_exp2f(s0[half * 8 + 4]),
                        __builtin_amdgcn_exp2f(s0[half * 8 + 5]));
      unsigned p3 = pk2(__builtin_amdgcn_exp2f(s0[half * 8 + 6]),
                        __builtin_amdgcn_exp2f(s0[half * 8 + 7]));
      asm("v_permlane32_swap_b32 %0, %1" : "+v"(p0), "+v"(p2));
      asm("v_permlane32_swap_b32 %0, %1" : "+v"(p1), "+v"(p3));
      union { unsigned u[4]; s16x8 v; } pf;
      pf.u[0] = p0; pf.u[1] = p1; pf.u[2] = p2; pf.u[3] = p3;
      const int kb = 2 * half + hi;
      __builtin_amdgcn_s_setprio(1);
#pragma unroll
      for (int mt = 0; mt < 2; ++mt) {
        s16x8 vfrag = *(const s16x8*)&Vt2[(kb * 65 + mt * 32 + l31) * 8];
        o[mt] = __builtin_amdgcn_mfma_f32_32x32x16_bf16(vfrag, pf.v, o[mt], 0, 0, 0);
      }
      __builtin_amdgcn_s_setprio(0);
    }

    // ---- QK^T s1 (key block 1: slots 3..5), then fused exp/pack/PV ks=2,3 ----
    f32x16 s1;
#pragma unroll
    for (int r = 0; r < 16; ++r) s1[r] = 0.f;
    __builtin_amdgcn_s_setprio(1);
#pragma unroll
    for (int ks = 0; ks < 3; ++ks) {
      s16x8 a1 = *(const s16x8*)&kf[((3 + ks) * 64 + lane) * 8];
      s1 = __builtin_amdgcn_mfma_f32_32x32x16_bf16(a1, qf[ks], s1, 0, 0, 0);
    }
    __builtin_amdgcn_s_setprio(0);
#pragma unroll
    for (int half = 0; half < 2; ++half) {
      unsigned p0 = pk2(__builtin_amdgcn_exp2f(s1[half * 8 + 0]),
                        __builtin_amdgcn_exp2f(s1[half * 8 + 1]));
      unsigned p1 = pk2(__builtin_amdgcn_exp2f(s1[half * 8 + 2]),
                        __builtin_amdgcn_exp2f(s1[half * 8 + 3]));
      unsigned p2 = pk2(__builtin_amdgcn_exp2f(s1[half * 8 + 4]),
                        __builtin_amdgcn_exp2f(s1[half * 8 + 5]));
      unsigned p3 = pk2(__builtin_amdgcn_exp2f(s1[half * 8 + 6]),
                        __builtin_amdgcn_exp2f(s1[half * 8 + 7]));
      asm("v_permlane32_swap_b32 %0, %1" : "+v"(p0), "+v"(p2));
      asm("v_permlane32_swap_b32 %0, %1" : "+v"(p1), "+v"(p3));
      union { unsigned u[4]; s16x8 v; } pf;
      pf.u[0] = p0; pf.u[1] = p1; pf.u[2] = p2; pf.u[3] = p3;
      const int kb = 2 * (2 + half) + hi;
      __builtin_amdgcn_s_setprio(1);
#pragma unroll
      for (int mt = 0; mt < 2; ++mt) {
        s16x8 vfrag = *(const s16x8*)&Vt2[(kb * 65 + mt * 32 + l31) * 8];
        o[mt] = __builtin_amdgcn_mfma_f32_32x32x16_bf16(vfrag, pf.v, o[mt], 0, 0, 0);
      }
      __builtin_amdgcn_s_setprio(0);
    }
  }

  // ---- epilogue: l = o[1][8] (hd 48 = ones row, hi=0 half); normalize ----
  const float lsum = __shfl(o[1][8], l31, 64);
  const float inv = 1.f / lsum;
  const int token = qt * QPB + w * QPW + l31;
  ushort_t* dst = Aout + ((size_t)b * SEQ + token) * DIMD + h * HD;
#pragma unroll
  for (int rq = 0; rq < 4; ++rq) {      // m-tile0: hd = 8*rq + 4*hi + {0..3}
    const int hd0 = 8 * rq + 4 * hi;
    uint2 pk;
    pk.x = pk2(o[0][4 * rq + 0] * inv, o[0][4 * rq + 1] * inv);
    pk.y = pk2(o[0][4 * rq + 2] * inv, o[0][4 * rq + 3] * inv);
    *(uint2*)(dst + hd0) = pk;
  }
#pragma unroll
  for (int rq = 0; rq < 2; ++rq) {      // m-tile1: hd = 32 + 8*rq + 4*hi + {0..3}
    const int hd0 = 32 + 8 * rq + 4 * hi;
    uint2 pk;
    pk.x = pk2(o[1][4 * rq + 0] * inv, o[1][4 * rq + 1] * inv);
    pk.y = pk2(o[1][4 * rq + 2] * inv, o[1][4 * rq + 3] * inv);
    *(uint2*)(dst + hd0) = pk;
  }
}

// ---------------------------------------------------------------------------
extern "C" void kernel_launch(void* const* d_in, const int* in_sizes, int n_in,
                              void* d_out, int out_size, void* d_ws, size_t ws_size,
                              hipStream_t stream) {
  const float* x      = (const float*)d_in[0];
  const float* w_qkv  = (const float*)d_in[1];
  const float* w_proj = (const float*)d_in[2];
  const float* b_proj = (const float*)d_in[3];
  float* out = (float*)d_out;

  ushort_t* xb     = (ushort_t*)d_ws;                  // [8192,768]  bf16
  ushort_t* wqkvT  = xb + (size_t)NTOK * DIMD;         // [2304,768]  bf16 (T)
  ushort_t* wprojT = wqkvT + (size_t)QKVD * DIMD;      // [768,768]   bf16 (T)
  ushort_t* qkv    = wprojT + (size_t)DIMD * DIMD;     // [8192,2304] bf16
  ushort_t* att    = qkv + (size_t)NTOK * QKVD;        // [8192,768]  bf16

  cvt_all<<<CVT_NB + TQ_NB + TP_NB, 256, 0, stream>>>(
      x, xb, w_qkv, wqkvT, w_proj, wprojT);

  gemm_bf16<1><<<dim3(QKVD / 128, NTOK / 128), 256, 0, stream>>>(
      xb, wqkvT, nullptr, qkv, NTOK, QKVD, DIMD);

  attn_mfma<<<dim3(BATCH * HEADS, SEQ / QPB), 512, 0, stream>>>(qkv, att);

  gemm_bf16<0><<<dim3(DIMD / 128, NTOK / 128), 256, 0, stream>>>(
      att, wprojT, b_proj, out, NTOK, DIMD, DIMD);
}

// Round 14
// 140.833 us; speedup vs baseline: 1.0475x; 1.0475x over previous
//
#include <hip/hip_runtime.h>
#include <hip/hip_bf16.h>

// Problem constants
#define DIMD   768
#define HEADS  16
#define HD     48
#define SEQ    2048
#define BATCH  4
#define NTOK   (BATCH * SEQ)     // 8192
#define QKVD   (3 * DIMD)        // 2304

typedef __attribute__((ext_vector_type(8)))  short s16x8;
typedef __attribute__((ext_vector_type(4)))  float f32x4;
typedef __attribute__((ext_vector_type(16))) float f32x16;
typedef unsigned short ushort_t;

static __device__ __forceinline__ unsigned short f2b(float f) {
  union { __hip_bfloat16 b; unsigned short s; } u;
  u.b = __float2bfloat16(f);
  return u.s;
}
static __device__ __forceinline__ float b2f(unsigned short v) {
  union { float f; unsigned u; } x;
  x.u = ((unsigned)v) << 16;
  return x.f;
}
static __device__ __forceinline__ unsigned pk2(float a, float b) {
  return (unsigned)f2b(a) | ((unsigned)f2b(b) << 16);
}

static __device__ __forceinline__ void gload_lds16(const void* g, void* l) {
  __builtin_amdgcn_global_load_lds(
      (const __attribute__((address_space(1))) unsigned int*)g,
      (__attribute__((address_space(3))) unsigned int*)l, 16, 0, 0);
}

// ---------------------------------------------------------------------------
// merged convert kernel: one launch does
//   blocks [0, 3072)        : x fp32 -> bf16 row-major (8 elems/thread)
//   blocks [3072, 4800)     : w_qkv transpose+cvt  [768][2304] -> [2304][768]
//   blocks [4800, 5376)     : w_proj transpose+cvt [768][768]  -> [768][768]
// ---------------------------------------------------------------------------
#define CVT_NB   (NTOK * DIMD / 8 / 256)          // 3072
#define TQ_NBX   (QKVD / 32)                      // 72
#define TQ_NB    (TQ_NBX * (DIMD / 32))           // 1728
#define TP_NBX   (DIMD / 32)                      // 24
#define TP_NB    (TP_NBX * (DIMD / 32))           // 576

__global__ __launch_bounds__(256) void cvt_all(
    const float* __restrict__ x, ushort_t* __restrict__ xb,
    const float* __restrict__ wq, ushort_t* __restrict__ wqT,
    const float* __restrict__ wp, ushort_t* __restrict__ wpT) {
  __shared__ float T[32][33];
  const int bid = blockIdx.x;
  const int tid = threadIdx.x;

  if (bid < CVT_NB) {
    const int i = bid * 256 + tid;                // < NTOK*DIMD/8 exactly
    float4 a = ((const float4*)x)[i * 2];
    float4 b = ((const float4*)x)[i * 2 + 1];
    s16x8 v;
    v[0] = (short)f2b(a.x); v[1] = (short)f2b(a.y);
    v[2] = (short)f2b(a.z); v[3] = (short)f2b(a.w);
    v[4] = (short)f2b(b.x); v[5] = (short)f2b(b.y);
    v[6] = (short)f2b(b.z); v[7] = (short)f2b(b.w);
    ((s16x8*)xb)[i] = v;
    return;
  }

  const float* in;
  ushort_t* out;
  int R, C, c0, r0;
  if (bid < CVT_NB + TQ_NB) {
    const int b1 = bid - CVT_NB;
    in = wq; out = wqT; R = DIMD; C = QKVD;
    c0 = (b1 % TQ_NBX) * 32; r0 = (b1 / TQ_NBX) * 32;
  } else {
    const int b2 = bid - CVT_NB - TQ_NB;
    in = wp; out = wpT; R = DIMD; C = DIMD;
    c0 = (b2 % TP_NBX) * 32; r0 = (b2 / TP_NBX) * 32;
  }
  const int lc = tid & 31, lr = tid >> 5;
#pragma unroll
  for (int i = 0; i < 4; ++i)
    T[lr + 8 * i][lc] = in[(size_t)(r0 + lr + 8 * i) * C + c0 + lc];
  __syncthreads();
#pragma unroll
  for (int i = 0; i < 4; ++i)
    out[(size_t)(c0 + lr + 8 * i) * R + r0 + lc] = f2b(T[lc][lr + 8 * i]);
}

// ---------------------------------------------------------------------------
// bf16 MFMA GEMM (m97 structure) + T1 XCD-bijective block swizzle:
// HW assigns block orig -> XCD orig%8; remap so each XCD processes a
// CONTIGUOUS range of (m,n) tiles (8 m-rows x all n) -> A/B panels stay
// L2-resident per XCD. Bijective since grid counts are multiples of 8.
// ---------------------------------------------------------------------------
template <int OUT_BF16>
__global__ __launch_bounds__(256) void gemm_bf16(
    const ushort_t* __restrict__ A, const ushort_t* __restrict__ Bt,
    const float* __restrict__ bias, void* __restrict__ Cout,
    int M, int N, int K) {
  __shared__ __align__(16) ushort_t As[128 * 64];
  __shared__ __align__(16) ushort_t Bs[128 * 64];

  const int tid = threadIdx.x;
  const int lane = tid & 63;
  const int w = tid >> 6;

  // --- XCD swizzle (identity if grid not divisible by 8) ---
  const int nwg = gridDim.x * gridDim.y;
  int bx = blockIdx.x, by = blockIdx.y;
  if ((nwg & 7) == 0) {
    const int orig = by * gridDim.x + bx;
    const int cpx = nwg >> 3;
    const int nid = (orig & 7) * cpx + (orig >> 3);
    bx = nid % gridDim.x;
    by = nid / gridDim.x;
  }
  const int m0 = by * 128, n0 = bx * 128;
  const int wm = (w >> 1) * 64, wn = (w & 1) * 64;

  const int c16s = (tid & 7) ^ ((tid >> 3) & 7);
  const ushort_t* aSrc = A + (size_t)(m0 + (tid >> 3)) * K + c16s * 8;
  const ushort_t* bSrc = Bt + (size_t)(n0 + (tid >> 3)) * K + c16s * 8;

  f32x4 acc[4][4];
#pragma unroll
  for (int i = 0; i < 4; ++i)
#pragma unroll
    for (int j = 0; j < 4; ++j) {
      acc[i][j][0] = 0.f; acc[i][j][1] = 0.f;
      acc[i][j][2] = 0.f; acc[i][j][3] = 0.f;
    }

  for (int k0 = 0; k0 < K; k0 += 64) {
    __syncthreads();
#pragma unroll
    for (int r = 0; r < 4; ++r) {
      gload_lds16(aSrc + (size_t)(r * 32) * K + k0,
                  (char*)As + (r * 256 + w * 64) * 16);
      gload_lds16(bSrc + (size_t)(r * 32) * K + k0,
                  (char*)Bs + (r * 256 + w * 64) * 16);
    }
    __syncthreads();

#pragma unroll
    for (int ks = 0; ks < 2; ++ks) {
      s16x8 af[4], bfr[4];
#pragma unroll
      for (int i = 0; i < 4; ++i) {
        const int ar = wm + i * 16 + (lane & 15);
        const int ac = (ks * 4 + (lane >> 4)) ^ (ar & 7);
        af[i] = *(const s16x8*)&As[ar * 64 + ac * 8];
        const int br = wn + i * 16 + (lane & 15);
        const int bc = (ks * 4 + (lane >> 4)) ^ (br & 7);
        bfr[i] = *(const s16x8*)&Bs[br * 64 + bc * 8];
      }
#pragma unroll
      for (int i = 0; i < 4; ++i)
#pragma unroll
        for (int j = 0; j < 4; ++j)
          acc[i][j] = __builtin_amdgcn_mfma_f32_16x16x32_bf16(
              af[i], bfr[j], acc[i][j], 0, 0, 0);
    }
  }

  if (OUT_BF16) {
    ushort_t* C = (ushort_t*)Cout;
#pragma unroll
    for (int i = 0; i < 4; ++i)
#pragma unroll
      for (int j = 0; j < 4; ++j) {
        const int col = n0 + wn + j * 16 + (lane & 15);
#pragma unroll
        for (int r = 0; r < 4; ++r) {
          const int row = m0 + wm + i * 16 + (lane >> 4) * 4 + r;
          C[(size_t)row * N + col] = f2b(acc[i][j][r]);
        }
      }
  } else {
    float* C = (float*)Cout;
#pragma unroll
    for (int i = 0; i < 4; ++i)
#pragma unroll
      for (int j = 0; j < 4; ++j) {
        const int col = n0 + wn + j * 16 + (lane & 15);
        const float bv = bias ? bias[col] : 0.f;
#pragma unroll
        for (int r = 0; r < 4; ++r) {
          const int row = m0 + wm + i * 16 + (lane >> 4) * 4 + r;
          C[(size_t)row * N + col] = acc[i][j][r] + bv;
        }
      }
  }
}

// ---------------------------------------------------------------------------
// bf16-MFMA flash attention — round-11 structure (best verified: 73.9 µs,
// bank-conflict-free Vt2, raw-exp2 softmax, l via ones-row in Vt2).
// ---------------------------------------------------------------------------
#define KVB 64
#define QPW 32
#define QPB 256
#define NT  (SEQ / KVB)

__global__ __launch_bounds__(512) void attn_mfma(const ushort_t* __restrict__ QKV,
                                                 ushort_t* __restrict__ Aout) {
  const int bh = blockIdx.x;   // fast dim: q-tiles of one (b,h) share an XCD
  const int qt = blockIdx.y;
  const int b = bh >> 4, h = bh & 15;
  const int tid  = threadIdx.x;
  const int w    = tid >> 6;      // 0..7
  const int lane = tid & 63;
  const int l31  = lane & 31;
  const int hi   = lane >> 5;

  __shared__ __align__(16) ushort_t Kfrag[6 * 64 * 8];  // 6 KB [slot][pos^slot][8]
  __shared__ __align__(16) ushort_t Vt2[8 * 65 * 8];    // 8.1 KB [kb][hd(pad65)][key%8]

  // zero Vt2, BARRIER, then ones row hd=48 (l accumulator row)
  *(uint4*)&Vt2[tid * 8] = make_uint4(0u, 0u, 0u, 0u);
  if (tid < 8) *(uint4*)&Vt2[4096 + tid * 8] = make_uint4(0u, 0u, 0u, 0u);
  __syncthreads();
  if (tid < 64) Vt2[((tid >> 3) * 65 + 48) * 8 + (tid & 7)] = (ushort_t)0x3F80;

  const ushort_t* qkv_b = QKV + (size_t)b * SEQ * QKVD;

  // --- Q fragments, pre-scaled by SCALE*log2(e) ---
  const float qs = 0.14433756729740643f * 1.44269504088896340f;
  const int qrow = qt * QPB + w * QPW + l31;
  const ushort_t* qsrc = qkv_b + (size_t)qrow * QKVD + h * HD;
  s16x8 qf[3];
#pragma unroll
  for (int ks = 0; ks < 3; ++ks) {
    s16x8 raw = *(const s16x8*)(qsrc + ks * 16 + hi * 8);
    s16x8 v;
#pragma unroll
    for (int j = 0; j < 8; ++j) v[j] = (short)f2b(b2f((unsigned short)raw[j]) * qs);
    qf[ks] = v;
  }

  f32x16 o[2];
#pragma unroll
  for (int mt = 0; mt < 2; ++mt)
#pragma unroll
    for (int r = 0; r < 16; ++r) o[mt][r] = 0.f;

  // staging: lane = key row; wave w = hd-granule (waves 0..5 only)
  const int srow = lane;
  const int g0 = w;
  const ushort_t* kv0 = qkv_b + (size_t)srow * QKVD + DIMD + h * HD;

  s16x8 ka, va;
  auto loadKV = [&](int kt) {
    if (g0 < 6) {
      const ushort_t* base = kv0 + (size_t)(kt * KVB) * QKVD;
      ka = *(const s16x8*)(base + g0 * 8);
      va = *(const s16x8*)(base + DIMD + g0 * 8);
    }
  };
  auto writeKV = [&]() {
    if (g0 < 6) {
      const int slot = (srow >> 5) * 3 + (g0 >> 1);
      const int pos = (((srow & 31) + ((g0 & 1) << 5)) ^ slot);
      *(s16x8*)&Kfrag[(slot * 64 + pos) * 8] = ka;
      const int kb = srow >> 3, k7 = srow & 7;
#pragma unroll
      for (int j = 0; j < 8; ++j)
        Vt2[(kb * 65 + 8 * g0 + j) * 8 + k7] = (ushort_t)va[j];
    }
  };

  loadKV(0);

  for (int kt = 0; kt < NT; ++kt) {
    __syncthreads();   // LDS readers of previous tile done
    writeKV();
    __syncthreads();   // K/V tile ready
    if (kt + 1 < NT) loadKV(kt + 1);   // T14: lands during compute

    // ---- QK^T swapped: S^T[key][q], two 32-key halves ----
    f32x16 s0, s1;
#pragma unroll
    for (int r = 0; r < 16; ++r) { s0[r] = 0.f; s1[r] = 0.f; }
    __builtin_amdgcn_s_setprio(1);
#pragma unroll
    for (int ks = 0; ks < 3; ++ks) {
      s16x8 a0 = *(const s16x8*)&Kfrag[(ks * 64 + (lane ^ ks)) * 8];
      s0 = __builtin_amdgcn_mfma_f32_32x32x16_bf16(a0, qf[ks], s0, 0, 0, 0);
      s16x8 a1 = *(const s16x8*)&Kfrag[((3 + ks) * 64 + (lane ^ (3 + ks))) * 8];
      s1 = __builtin_amdgcn_mfma_f32_32x32x16_bf16(a1, qf[ks], s1, 0, 0, 0);
    }
    __builtin_amdgcn_s_setprio(0);

    // ---- softmax numerator: exp2 raw (logits bounded), pack to bf16 ----
    unsigned pw0[8], pw1[8];
#pragma unroll
    for (int g = 0; g < 8; ++g) {
      pw0[g] = pk2(__builtin_amdgcn_exp2f(s0[2 * g]),
                   __builtin_amdgcn_exp2f(s0[2 * g + 1]));
      pw1[g] = pk2(__builtin_amdgcn_exp2f(s1[2 * g]),
                   __builtin_amdgcn_exp2f(s1[2 * g + 1]));
    }

    // ---- PV: O^T += V^T @ P^T ; P^T B-frags via permlane32_swap ----
    __builtin_amdgcn_s_setprio(1);
#pragma unroll
    for (int ks = 0; ks < 4; ++ks) {
      unsigned w0 = (ks < 2) ? pw0[4 * (ks & 1) + 0] : pw1[4 * (ks & 1) + 0];
      unsigned w1 = (ks < 2) ? pw0[4 * (ks & 1) + 1] : pw1[4 * (ks & 1) + 1];
      unsigned w2 = (ks < 2) ? pw0[4 * (ks & 1) + 2] : pw1[4 * (ks & 1) + 2];
      unsigned w3 = (ks < 2) ? pw0[4 * (ks & 1) + 3] : pw1[4 * (ks & 1) + 3];
      asm("v_permlane32_swap_b32 %0, %1" : "+v"(w0), "+v"(w2));
      asm("v_permlane32_swap_b32 %0, %1" : "+v"(w1), "+v"(w3));
      union { unsigned u[4]; s16x8 v; } pf;
      pf.u[0] = w0; pf.u[1] = w1; pf.u[2] = w2; pf.u[3] = w3;
      const int kb = 2 * ks + hi;   // key-block = (ks*16 + hi*8) / 8
#pragma unroll
      for (int mt = 0; mt < 2; ++mt) {
        const int hd = mt * 32 + l31;
        s16x8 vfrag = *(const s16x8*)&Vt2[(kb * 65 + hd) * 8];
        o[mt] = __builtin_amdgcn_mfma_f32_32x32x16_bf16(vfrag, pf.v, o[mt], 0, 0, 0);
      }
    }
    __builtin_amdgcn_s_setprio(0);
  }

  // ---- epilogue: l = o[1][8] (hd 48 = ones row, hi=0 half); normalize ----
  const float lsum = __shfl(o[1][8], l31, 64);
  const float inv = 1.f / lsum;
  const int token = qt * QPB + w * QPW + l31;
  ushort_t* dst = Aout + ((size_t)b * SEQ + token) * DIMD + h * HD;
#pragma unroll
  for (int rq = 0; rq < 4; ++rq) {      // m-tile0: hd = 8*rq + 4*hi + {0..3}
    const int hd0 = 8 * rq + 4 * hi;
    uint2 pk;
    pk.x = pk2(o[0][4 * rq + 0] * inv, o[0][4 * rq + 1] * inv);
    pk.y = pk2(o[0][4 * rq + 2] * inv, o[0][4 * rq + 3] * inv);
    *(uint2*)(dst + hd0) = pk;
  }
#pragma unroll
  for (int rq = 0; rq < 2; ++rq) {      // m-tile1: hd = 32 + 8*rq + 4*hi + {0..3}
    const int hd0 = 32 + 8 * rq + 4 * hi;
    uint2 pk;
    pk.x = pk2(o[1][4 * rq + 0] * inv, o[1][4 * rq + 1] * inv);
    pk.y = pk2(o[1][4 * rq + 2] * inv, o[1][4 * rq + 3] * inv);
    *(uint2*)(dst + hd0) = pk;
  }
}

// ---------------------------------------------------------------------------
extern "C" void kernel_launch(void* const* d_in, const int* in_sizes, int n_in,
                              void* d_out, int out_size, void* d_ws, size_t ws_size,
                              hipStream_t stream) {
  const float* x      = (const float*)d_in[0];
  const float* w_qkv  = (const float*)d_in[1];
  const float* w_proj = (const float*)d_in[2];
  const float* b_proj = (const float*)d_in[3];
  float* out = (float*)d_out;

  ushort_t* xb     = (ushort_t*)d_ws;                  // [8192,768]  bf16
  ushort_t* wqkvT  = xb + (size_t)NTOK * DIMD;         // [2304,768]  bf16 (T)
  ushort_t* wprojT = wqkvT + (size_t)QKVD * DIMD;      // [768,768]   bf16 (T)
  ushort_t* qkv    = wprojT + (size_t)DIMD * DIMD;     // [8192,2304] bf16
  ushort_t* att    = qkv + (size_t)NTOK * QKVD;        // [8192,768]  bf16

  // one merged convert launch (x cvt + both weight transposes)
  cvt_all<<<CVT_NB + TQ_NB + TP_NB, 256, 0, stream>>>(
      x, xb, w_qkv, wqkvT, w_proj, wprojT);

  gemm_bf16<1><<<dim3(QKVD / 128, NTOK / 128), 256, 0, stream>>>(
      xb, wqkvT, nullptr, qkv, NTOK, QKVD, DIMD);

  attn_mfma<<<dim3(BATCH * HEADS, SEQ / QPB), 512, 0, stream>>>(qkv, att);

  gemm_bf16<0><<<dim3(DIMD / 128, NTOK / 128), 256, 0, stream>>>(
      att, wprojT, b_proj, out, NTOK, DIMD, DIMD);
}